// Round 18
// baseline (149.228 us; speedup 1.0000x reference)
//
#include <hip/hip_runtime.h>
#include <hip/hip_bf16.h>

#define EMB   128
#define HEADS 8
#define HC    (HEADS * EMB)   // 1024
#define NEG   0.2f

typedef __attribute__((ext_vector_type(8))) short  short8;   // 8 bf16 (4 VGPRs)
typedef __attribute__((ext_vector_type(4))) float  floatx4;  // MFMA accumulator
typedef __attribute__((ext_vector_type(2))) float  floatx2;

// decode 4 fp8 (e4m3) packed in a dword -> 4 floats (HW cvt, 2 per op)
static __device__ __forceinline__ void cvt4(unsigned int u, float* o)
{
    floatx2 lo = __builtin_amdgcn_cvt_pk_f32_fp8(u, false);
    floatx2 hi = __builtin_amdgcn_cvt_pk_f32_fp8(u, true);
    o[0] = lo[0]; o[1] = lo[1]; o[2] = hi[0]; o[3] = hi[1];
}

// ---------------------------------------------------------------------------
// PREP mega-kernel: disjoint block ranges do
//   [0,nbA)   cvt_x   : x fp32 -> xb bf16 (4/thread)
//   [nbA,nbB) cvt_wt  : W transpose via padded LDS tile (coalesced both sides)
//   [nbB,nbC) count_deg
//   [nbC,nbD) write_ei: full_edge_index as fp32 to d_out
// ---------------------------------------------------------------------------
__global__ void prep(const float* __restrict__ x,
                     const float* __restrict__ W_l,
                     const float* __restrict__ W_r,
                     const int* __restrict__ ei,
                     __hip_bfloat16* __restrict__ xb,
                     __hip_bfloat16* __restrict__ WtL,
                     __hip_bfloat16* __restrict__ WtR,
                     int* __restrict__ deg,
                     float* __restrict__ out_ei,
                     int N, int E, int nbA, int nbB, int nbC)
{
    __shared__ __hip_bfloat16 wtile[64][130];   // +2 pad: conflict-free
    int b = blockIdx.x, t = threadIdx.x;
    int Et = E + N;
    if (b < nbA) {
        int i = b * 256 + t;
        int n4 = N * EMB / 4;
        if (i >= n4) return;
        const float4 v = ((const float4*)x)[i];
        __hip_bfloat16 o[4] = { __float2bfloat16(v.x), __float2bfloat16(v.y),
                                __float2bfloat16(v.z), __float2bfloat16(v.w) };
        *(uint2*)(xb + (size_t)i * 4) = *(const uint2*)o;
    } else if (b < nbB) {
        // 32 blocks: b2>>4 picks matrix, (b2&15)*64 is the n0 column slab
        int b2 = b - nbA;
        const float* W = (b2 < 16) ? W_l : W_r;
        __hip_bfloat16* Wt = (b2 < 16) ? WtL : WtR;
        int n0 = (b2 & 15) * 64;
        int nl = t & 63;
#pragma unroll
        for (int r = 0; r < 32; ++r) {
            int k = r * 4 + (t >> 6);
            wtile[nl][k] = __float2bfloat16(W[(size_t)k * HC + n0 + nl]);
        }
        __syncthreads();
        int row = t >> 2, ck = (t & 3) * 32;
        __hip_bfloat16* dst = Wt + (size_t)(n0 + row) * EMB + ck;
#pragma unroll
        for (int c = 0; c < 4; ++c)
            *(uint4*)(dst + c * 8) = *(const uint4*)(&wtile[row][ck + c * 8]);
    } else if (b < nbC) {
        int e = (b - nbB) * 256 + t;
        if (e >= Et) return;
        int dst = (e < E) ? ei[E + e] : (e - E);
        atomicAdd(&deg[dst], 1);
    } else {
        int i = (b - nbC) * 256 + t;
        if (i >= 2 * Et) return;
        int row = i / Et, col = i - row * Et;
        int v = (col < E) ? ei[row * E + col] : (col - E);
        out_ei[i] = (float)v;
    }
}

// ---------------------------------------------------------------------------
// Exclusive scan of deg -> offs (+cursor). Single block, 1024 threads.
// ---------------------------------------------------------------------------
__global__ void scan_offsets(const int* __restrict__ deg, int N,
                             int* __restrict__ offs, int* __restrict__ cursor)
{
    __shared__ int part[1024];
    int t = threadIdx.x;
    int CH = (N + 1023) / 1024;
    int base = t * CH;
    int s = 0;
    for (int i = 0; i < CH; ++i) {
        int idx = base + i;
        if (idx < N) s += deg[idx];
    }
    part[t] = s;
    __syncthreads();
    for (int d = 1; d < 1024; d <<= 1) {
        int v = (t >= d) ? part[t - d] : 0;
        __syncthreads();
        part[t] += v;
        __syncthreads();
    }
    int run = (t == 0) ? 0 : part[t - 1];
    for (int i = 0; i < CH; ++i) {
        int idx = base + i;
        if (idx < N) { offs[idx] = run; cursor[idx] = run; run += deg[idx]; }
    }
    if (t == 1023) offs[N] = run;
}

// ---------------------------------------------------------------------------
// MID: blocks [0,nbF) fill CSR (int2 e,src) — runs CONCURRENT with the GEMM
// blocks [nbF,...) (r12 arrangement; serializing fill after gemm cost ~6us).
// GEMM: 128x128 MFMA tile, fp8 out via swizzled LDS; epilogue also emits
// dot[n][h] = 0.6 * att[h].row_n (linear part of the split GATv2 score).
// ---------------------------------------------------------------------------
__global__ void mid(const int* __restrict__ ei, int E, int N,
                    int* __restrict__ cursor, int2* __restrict__ csr,
                    const __hip_bfloat16* __restrict__ xb,
                    const __hip_bfloat16* __restrict__ WtL,
                    const __hip_bfloat16* __restrict__ WtR,
                    const float* __restrict__ b_l,
                    const float* __restrict__ b_r,
                    const float* __restrict__ att,
                    unsigned char* __restrict__ xl8,
                    unsigned char* __restrict__ xr8,
                    float* __restrict__ dotL,
                    float* __restrict__ dotR,
                    int M, int nbF, int gx, int gy)
{
    __shared__ uint4 stile4[1024];               // 16 KB fp8 tile
    unsigned char* stile = (unsigned char*)stile4;

    int b = blockIdx.x, t = threadIdx.x;
    if (b < nbF) {
        int e = b * 256 + t;
        if (e >= E + N) return;
        int dst, src;
        if (e < E) { dst = ei[E + e]; src = ei[e]; } else { dst = src = e - E; }
        int pos = atomicAdd(&cursor[dst], 1);
        csr[pos] = make_int2(e, src);
        return;
    }

    int idx = b - nbF;
    int per_z = gx * gy;
    int bz = idx / per_z;
    int rem = idx - bz * per_z;
    int by = rem / gx;          // head index (128 cols = one head)
    int bx = rem - by * gx;

    const __hip_bfloat16* Wt = bz ? WtR : WtL;
    const float* bb           = bz ? b_r : b_l;
    unsigned char* out        = bz ? xr8 : xl8;
    float* dotOut             = bz ? dotR : dotL;

    int wave = t >> 6;
    int lane = t & 63;
    int lr   = lane & 15;
    int lkq  = lane >> 4;
    int lk   = lkq * 8;
    int mb   = bx * 128;
    int n0   = by * 128;

    short8 afr[2][4];
#pragma unroll
    for (int rt = 0; rt < 2; ++rt) {
        int arow = mb + wave * 32 + rt * 16 + lr;
        if (arow >= M) arow = M - 1;
        const short* Ap = (const short*)xb + (size_t)arow * EMB + lk;
#pragma unroll
        for (int kk = 0; kk < 4; ++kk)
            afr[rt][kk] = *(const short8*)(Ap + kk * 32);
    }

    floatx4 acc[2][8];
#pragma unroll
    for (int rt = 0; rt < 2; ++rt)
#pragma unroll
        for (int nc = 0; nc < 8; ++nc)
            acc[rt][nc] = floatx4{0.f, 0.f, 0.f, 0.f};

#pragma unroll
    for (int kk = 0; kk < 4; ++kk) {
        short8 bfr[8];
#pragma unroll
        for (int nc = 0; nc < 8; ++nc)
            bfr[nc] = *(const short8*)((const short*)Wt +
                        (size_t)(n0 + nc * 16 + lr) * EMB + kk * 32 + lk);
#pragma unroll
        for (int nc = 0; nc < 8; ++nc) {
            acc[0][nc] = __builtin_amdgcn_mfma_f32_16x16x32_bf16(afr[0][kk], bfr[nc], acc[0][nc], 0, 0, 0);
            acc[1][nc] = __builtin_amdgcn_mfma_f32_16x16x32_bf16(afr[1][kk], bfr[nc], acc[1][nc], 0, 0, 0);
        }
    }

    // att values for this lane's columns (channel = nc*16 + lr of head by)
    float att_v[8];
#pragma unroll
    for (int nc = 0; nc < 8; ++nc)
        att_v[nc] = att[by * EMB + nc * 16 + lr];

    float drow[2][4] = {{0.f,0.f,0.f,0.f},{0.f,0.f,0.f,0.f}};

#pragma unroll
    for (int rt = 0; rt < 2; ++rt) {
#pragma unroll
        for (int nc = 0; nc < 8; ++nc) {
            float bv = bb[n0 + nc * 16 + lr];
#pragma unroll
            for (int j = 0; j < 4; ++j) {
                int row = wave * 32 + rt * 16 + lkq * 4 + j;
                float v = acc[rt][nc][j] + bv;
                drow[rt][j] = fmaf(att_v[nc], v, drow[rt][j]);
                unsigned int p = __builtin_amdgcn_cvt_pk_fp8_f32(v, v, 0u, false);
                int col = ((nc * 16) ^ ((row & 7) << 4)) + lr;
                stile[row * 128 + col] = (unsigned char)(p & 0xFFu);
            }
        }
    }

    // reduce drow over the 16 lanes (lr) of each quadrant group, store 0.6*dot
#pragma unroll
    for (int rt = 0; rt < 2; ++rt) {
#pragma unroll
        for (int j = 0; j < 4; ++j) {
            float d = drow[rt][j];
            d += __shfl_xor(d, 1);
            d += __shfl_xor(d, 2);
            d += __shfl_xor(d, 4);
            d += __shfl_xor(d, 8);
            int r = mb + wave * 32 + rt * 16 + lkq * 4 + j;
            if (lr == 0 && r < M) dotOut[(size_t)r * HEADS + by] = 0.6f * d;
        }
    }
    __syncthreads();

#pragma unroll
    for (int q = 0; q < 4; ++q) {
        int idx2 = q * 256 + t;
        int row = idx2 >> 3;
        int c16 = (idx2 & 7) * 16;
        int r = mb + row;
        if (r < M)
            *(uint4*)(out + (size_t)r * HC + n0 + c16) =
                *(const uint4*)(stile + row * 128 + (c16 ^ ((row & 7) << 4)));
    }
}

// ---------------------------------------------------------------------------
// FUSED kernel — 2 blocks per node (4 heads each) to DOUBLE resident-thread
// count (the kernel is gather-latency-bound; per-thread pipelining failed
// 3x, so in-flight bytes must come from more threads). Per-edge lane work is
// identical to the proven r16 loop: 8B uint2 gather, 4-shfl reduce,
// split-score  sp = dotL[src]+dotR[n] + sum(0.4*att*|xl+xr|).
// Head group = 64 lanes = 4 edge-subs x 16 lanes x 8 channels.
// Cross-block head-mean via atomicAdd into zeroed latent (2 commutative
// fp32 adds -> bitwise deterministic).
// ---------------------------------------------------------------------------
__global__ void fused_node(const int* __restrict__ offs,
                           const int2* __restrict__ csr,
                           const unsigned char* __restrict__ xl8,
                           const unsigned char* __restrict__ xr8,
                           const float* __restrict__ dotL,
                           const float* __restrict__ dotR,
                           const float* __restrict__ att,
                           const float* __restrict__ bias,
                           float* __restrict__ alpha_out,
                           float* __restrict__ latent, int N)
{
    __shared__ float sacc[4 * EMB];
    __shared__ float sinv[4];

    int n   = blockIdx.x >> 1;
    int hb  = (blockIdx.x & 1) * 4;   // head base: 0 or 4
    int t   = threadIdx.x;
    int hl  = t >> 6;                 // local head 0..3
    int h   = hb + hl;
    int L   = t & 63;
    int sub = L >> 4;                 // edge-of-quad selector 0..3
    int q   = L & 15;                 // lane within 16
    int c0  = q * 8;                  // channel base (8 channels/thread)
    int uo  = h * 16 + q;             // uint2 offset within a 1024B row

    float av[8];
    {
        const float4* ap = (const float4*)(att + h * EMB + c0);
        float4 a0 = ap[0], a1 = ap[1];
        av[0]=a0.x*0.4f; av[1]=a0.y*0.4f; av[2]=a0.z*0.4f; av[3]=a0.w*0.4f;
        av[4]=a1.x*0.4f; av[5]=a1.y*0.4f; av[6]=a1.z*0.4f; av[7]=a1.w*0.4f;
    }
    const uint2* xlu = (const uint2*)xl8;
    const uint2* xru = (const uint2*)xr8;

    float rv[8];
    { uint2 r = xru[(size_t)n * 128 + uo]; cvt4(r.x, rv); cvt4(r.y, rv + 4); }
    float dr0 = dotR[(size_t)n * HEADS + h];     // 0.6-prescaled

    float acc[8] = {0,0,0,0,0,0,0,0};
    float S = 0.f;
    int js = offs[n], je = offs[n + 1];
    int jlast = je - 1;

    // preload first quad entry for this sub (clamped)
    int jc = js + sub;
    bool okc = jc < je;
    if (jc > jlast) jc = jlast;
    int2  cc = csr[jc];
    uint2 vc = xlu[(size_t)cc.y * 128 + uo];
    float dc = dotL[(size_t)cc.y * HEADS + h];

    for (int j = js; j < je; j += 4) {
        // preload next quad entry
        int jn = j + 4 + sub;
        bool okn = jn < je;
        if (jn > jlast) jn = jlast;
        int2  cn = csr[jn];
        uint2 vn = xlu[(size_t)cn.y * 128 + uo];
        float dn = dotL[(size_t)cn.y * HEADS + h];

        float xv[8];
        cvt4(vc.x, xv); cvt4(vc.y, xv + 4);
        float s0 = 0.f, s1 = 0.f;
#pragma unroll
        for (int i = 0; i < 8; i += 2) {
            float z0 = xv[i]   + rv[i];
            float z1 = xv[i+1] + rv[i+1];
            s0 = fmaf(av[i],   fabsf(z0), s0);   // |.| = free input modifier
            s1 = fmaf(av[i+1], fabsf(z1), s1);
        }
        float sp = s0 + s1;
        sp += __shfl_xor(sp, 1);
        sp += __shfl_xor(sp, 2);
        sp += __shfl_xor(sp, 4);
        sp += __shfl_xor(sp, 8);      // abs-part reduced within 16-lane sub
        sp += dc + dr0;               // + linear part (0.6-prescaled dots)

        float wq = okc ? __expf(sp) : 0.f;
        if (q == 0 && okc) alpha_out[(size_t)cc.x * HEADS + h] = wq;
        S += wq;
#pragma unroll
        for (int i = 0; i < 8; ++i) acc[i] = fmaf(wq, xv[i], acc[i]);

        vc = vn; cc = cn; dc = dn; okc = okn;
    }

    // merge the four subs (lanes ^16, ^32)
    S += __shfl_xor(S, 16);
    S += __shfl_xor(S, 32);
#pragma unroll
    for (int i = 0; i < 8; ++i) {
        acc[i] += __shfl_xor(acc[i], 16);
        acc[i] += __shfl_xor(acc[i], 32);
    }

    float inv = 1.f / (S + 1e-16f);
    if (L == 0) sinv[hl] = inv;
    if (sub == 0) {
#pragma unroll
        for (int i = 0; i < 8; ++i) sacc[hl * EMB + c0 + i] = acc[i] * inv;
    }
    __syncthreads();   // stashes + sinv + sacc visible block-wide

    // Pass 2: scale this block's 4 heads (64 edges x 4 heads per step)
    for (int j0 = js; j0 < je; j0 += 64) {
        int j = j0 + (t >> 2);
        if (j < je) {
            int lh = t & 3;
            size_t p = (size_t)csr[j].x * HEADS + hb + lh;
            alpha_out[p] *= sinv[lh];
        }
    }

    // Epilogue: partial head mean (4 heads) + bias once -> atomic combine
    if (t < EMB) {
        float sum = sacc[t] + sacc[EMB + t] + sacc[2 * EMB + t] + sacc[3 * EMB + t];
        float add = sum * 0.125f + (hb == 0 ? bias[t] : 0.f);
        atomicAdd(&latent[(size_t)n * EMB + t], add);
    }
}

// ---------------------------------------------------------------------------
extern "C" void kernel_launch(void* const* d_in, const int* in_sizes, int n_in,
                              void* d_out, int out_size, void* d_ws, size_t ws_size,
                              hipStream_t stream)
{
    const float* x    = (const float*)d_in[0];
    const float* W_l  = (const float*)d_in[1];
    const float* b_l  = (const float*)d_in[2];
    const float* W_r  = (const float*)d_in[3];
    const float* b_r  = (const float*)d_in[4];
    const float* att  = (const float*)d_in[5];
    const float* bias = (const float*)d_in[6];
    const int*   ei   = (const int*)d_in[7];

    int N  = in_sizes[0] / EMB;     // 10000
    int E  = in_sizes[7] / 2;       // 160000
    int Et = E + N;                 // 170000

    auto align256 = [](size_t v) { return (v + 255) & ~(size_t)255; };
    char* w = (char*)d_ws;
    int* deg      = (int*)w;    w += align256((size_t)N * 4);
    int* offs     = (int*)w;    w += align256((size_t)(N + 1) * 4);
    int* cursor   = (int*)w;    w += align256((size_t)N * 4);
    int2* csr     = (int2*)w;   w += align256((size_t)Et * 8);
    unsigned char* xl8 = (unsigned char*)w;   w += align256((size_t)N * HC);
    unsigned char* xr8 = (unsigned char*)w;   w += align256((size_t)N * HC);
    float* dotL   = (float*)w;  w += align256((size_t)N * HEADS * 4);
    float* dotR   = (float*)w;  w += align256((size_t)N * HEADS * 4);
    __hip_bfloat16* xb  = (__hip_bfloat16*)w;  w += align256((size_t)N * EMB * 2);
    __hip_bfloat16* WtL = (__hip_bfloat16*)w;  w += align256((size_t)EMB * HC * 2);
    __hip_bfloat16* WtR = (__hip_bfloat16*)w;  w += align256((size_t)EMB * HC * 2);

    // d_out fp32: latent[N*128] | full_edge_index[2*Et] | alpha[Et*8]
    float* out_latent = (float*)d_out;
    float* out_ei     = out_latent + (size_t)N * EMB;
    float* out_alpha  = out_ei + (size_t)2 * Et;

    hipMemsetAsync(deg, 0, (size_t)N * 4, stream);
    hipMemsetAsync(out_latent, 0, (size_t)N * EMB * 4, stream);  // atomic base

    int n4  = N * EMB / 4;
    int nbA = (n4 + 255) / 256;
    int nbB = nbA + 32;                       // 32 LDS-transpose blocks
    int nbC = nbB + (Et + 255) / 256;
    int nbD = nbC + (2 * Et + 255) / 256;
    prep<<<nbD, 256, 0, stream>>>(x, W_l, W_r, ei, xb, WtL, WtR, deg, out_ei,
                                  N, E, nbA, nbB, nbC);

    scan_offsets<<<1, 1024, 0, stream>>>(deg, N, offs, cursor);

    int nbF = (Et + 255) / 256;
    int gx = (N + 127) / 128, gy = HC / 128;
    mid<<<nbF + gx * gy * 2, 256, 0, stream>>>(ei, E, N, cursor, csr,
                                               xb, WtL, WtR, b_l, b_r, att,
                                               xl8, xr8, dotL, dotR,
                                               N, nbF, gx, gy);

    fused_node<<<2 * N, 256, 0, stream>>>(offs, csr, xl8, xr8, dotL, dotR,
                                          att, bias, out_alpha, out_latent, N);
}

// Round 19
// 124.104 us; speedup vs baseline: 1.2024x; 1.2024x over previous
//
#include <hip/hip_runtime.h>
#include <hip/hip_bf16.h>

#define EMB   128
#define HEADS 8
#define HC    (HEADS * EMB)   // 1024
#define NEG   0.2f

typedef __attribute__((ext_vector_type(8))) short  short8;   // 8 bf16 (4 VGPRs)
typedef __attribute__((ext_vector_type(4))) float  floatx4;  // MFMA accumulator
typedef __attribute__((ext_vector_type(2))) float  floatx2;

// decode 4 fp8 (e4m3) packed in a dword -> 4 floats (HW cvt, 2 per op)
static __device__ __forceinline__ void cvt4(unsigned int u, float* o)
{
    floatx2 lo = __builtin_amdgcn_cvt_pk_f32_fp8(u, false);
    floatx2 hi = __builtin_amdgcn_cvt_pk_f32_fp8(u, true);
    o[0] = lo[0]; o[1] = lo[1]; o[2] = hi[0]; o[3] = hi[1];
}

// ---------------------------------------------------------------------------
// PREP mega-kernel: disjoint block ranges do
//   [0,nbA)   cvt_x   : x fp32 -> xb bf16 (4/thread)
//   [nbA,nbB) cvt_wt  : W transpose via padded LDS tile (coalesced both sides)
//   [nbB,nbC) count_deg
//   [nbC,nbD) write_ei: full_edge_index as fp32 to d_out
// ---------------------------------------------------------------------------
__global__ void prep(const float* __restrict__ x,
                     const float* __restrict__ W_l,
                     const float* __restrict__ W_r,
                     const int* __restrict__ ei,
                     __hip_bfloat16* __restrict__ xb,
                     __hip_bfloat16* __restrict__ WtL,
                     __hip_bfloat16* __restrict__ WtR,
                     int* __restrict__ deg,
                     float* __restrict__ out_ei,
                     int N, int E, int nbA, int nbB, int nbC)
{
    __shared__ __hip_bfloat16 wtile[64][130];   // +2 pad: conflict-free
    int b = blockIdx.x, t = threadIdx.x;
    int Et = E + N;
    if (b < nbA) {
        int i = b * 256 + t;
        int n4 = N * EMB / 4;
        if (i >= n4) return;
        const float4 v = ((const float4*)x)[i];
        __hip_bfloat16 o[4] = { __float2bfloat16(v.x), __float2bfloat16(v.y),
                                __float2bfloat16(v.z), __float2bfloat16(v.w) };
        *(uint2*)(xb + (size_t)i * 4) = *(const uint2*)o;
    } else if (b < nbB) {
        // 32 blocks: b2>>4 picks matrix, (b2&15)*64 is the n0 column slab
        int b2 = b - nbA;
        const float* W = (b2 < 16) ? W_l : W_r;
        __hip_bfloat16* Wt = (b2 < 16) ? WtL : WtR;
        int n0 = (b2 & 15) * 64;
        int nl = t & 63;
#pragma unroll
        for (int r = 0; r < 32; ++r) {
            int k = r * 4 + (t >> 6);
            wtile[nl][k] = __float2bfloat16(W[(size_t)k * HC + n0 + nl]);
        }
        __syncthreads();
        int row = t >> 2, ck = (t & 3) * 32;
        __hip_bfloat16* dst = Wt + (size_t)(n0 + row) * EMB + ck;
#pragma unroll
        for (int c = 0; c < 4; ++c)
            *(uint4*)(dst + c * 8) = *(const uint4*)(&wtile[row][ck + c * 8]);
    } else if (b < nbC) {
        int e = (b - nbB) * 256 + t;
        if (e >= Et) return;
        int dst = (e < E) ? ei[E + e] : (e - E);
        atomicAdd(&deg[dst], 1);
    } else {
        int i = (b - nbC) * 256 + t;
        if (i >= 2 * Et) return;
        int row = i / Et, col = i - row * Et;
        int v = (col < E) ? ei[row * E + col] : (col - E);
        out_ei[i] = (float)v;
    }
}

// ---------------------------------------------------------------------------
// Exclusive scan of deg -> offs (+cursor). Single block, 1024 threads.
// ---------------------------------------------------------------------------
__global__ void scan_offsets(const int* __restrict__ deg, int N,
                             int* __restrict__ offs, int* __restrict__ cursor)
{
    __shared__ int part[1024];
    int t = threadIdx.x;
    int CH = (N + 1023) / 1024;
    int base = t * CH;
    int s = 0;
    for (int i = 0; i < CH; ++i) {
        int idx = base + i;
        if (idx < N) s += deg[idx];
    }
    part[t] = s;
    __syncthreads();
    for (int d = 1; d < 1024; d <<= 1) {
        int v = (t >= d) ? part[t - d] : 0;
        __syncthreads();
        part[t] += v;
        __syncthreads();
    }
    int run = (t == 0) ? 0 : part[t - 1];
    for (int i = 0; i < CH; ++i) {
        int idx = base + i;
        if (idx < N) { offs[idx] = run; cursor[idx] = run; run += deg[idx]; }
    }
    if (t == 1023) offs[N] = run;
}

// ---------------------------------------------------------------------------
// MID: blocks [0,nbF) fill CSR (int2 e,src) — runs CONCURRENT with the GEMM
// blocks [nbF,...) (r12 arrangement, best measured non-fused: 67.7us).
// GEMM: 128x128 MFMA tile, fp8 out via swizzled LDS, 128B row stores.
// No dot epilogue: split-score bought nothing (r15 fused == r16 fused).
// ---------------------------------------------------------------------------
__global__ void mid(const int* __restrict__ ei, int E, int N,
                    int* __restrict__ cursor, int2* __restrict__ csr,
                    const __hip_bfloat16* __restrict__ xb,
                    const __hip_bfloat16* __restrict__ WtL,
                    const __hip_bfloat16* __restrict__ WtR,
                    const float* __restrict__ b_l,
                    const float* __restrict__ b_r,
                    unsigned char* __restrict__ xl8,
                    unsigned char* __restrict__ xr8,
                    int M, int nbF, int gx, int gy)
{
    __shared__ uint4 stile4[1024];               // 16 KB fp8 tile
    unsigned char* stile = (unsigned char*)stile4;

    int b = blockIdx.x, t = threadIdx.x;
    if (b < nbF) {
        int e = b * 256 + t;
        if (e >= E + N) return;
        int dst, src;
        if (e < E) { dst = ei[E + e]; src = ei[e]; } else { dst = src = e - E; }
        int pos = atomicAdd(&cursor[dst], 1);
        csr[pos] = make_int2(e, src);
        return;
    }

    int idx = b - nbF;
    int per_z = gx * gy;
    int bz = idx / per_z;
    int rem = idx - bz * per_z;
    int by = rem / gx;
    int bx = rem - by * gx;

    const __hip_bfloat16* Wt = bz ? WtR : WtL;
    const float* bb           = bz ? b_r : b_l;
    unsigned char* out        = bz ? xr8 : xl8;

    int wave = t >> 6;
    int lane = t & 63;
    int lr   = lane & 15;
    int lkq  = lane >> 4;
    int lk   = lkq * 8;
    int mb   = bx * 128;
    int n0   = by * 128;

    short8 afr[2][4];
#pragma unroll
    for (int rt = 0; rt < 2; ++rt) {
        int arow = mb + wave * 32 + rt * 16 + lr;
        if (arow >= M) arow = M - 1;
        const short* Ap = (const short*)xb + (size_t)arow * EMB + lk;
#pragma unroll
        for (int kk = 0; kk < 4; ++kk)
            afr[rt][kk] = *(const short8*)(Ap + kk * 32);
    }

    floatx4 acc[2][8];
#pragma unroll
    for (int rt = 0; rt < 2; ++rt)
#pragma unroll
        for (int nc = 0; nc < 8; ++nc)
            acc[rt][nc] = floatx4{0.f, 0.f, 0.f, 0.f};

#pragma unroll
    for (int kk = 0; kk < 4; ++kk) {
        short8 bfr[8];
#pragma unroll
        for (int nc = 0; nc < 8; ++nc)
            bfr[nc] = *(const short8*)((const short*)Wt +
                        (size_t)(n0 + nc * 16 + lr) * EMB + kk * 32 + lk);
#pragma unroll
        for (int nc = 0; nc < 8; ++nc) {
            acc[0][nc] = __builtin_amdgcn_mfma_f32_16x16x32_bf16(afr[0][kk], bfr[nc], acc[0][nc], 0, 0, 0);
            acc[1][nc] = __builtin_amdgcn_mfma_f32_16x16x32_bf16(afr[1][kk], bfr[nc], acc[1][nc], 0, 0, 0);
        }
    }

#pragma unroll
    for (int rt = 0; rt < 2; ++rt) {
#pragma unroll
        for (int nc = 0; nc < 8; ++nc) {
            float bv = bb[n0 + nc * 16 + lr];
#pragma unroll
            for (int j = 0; j < 4; ++j) {
                int row = wave * 32 + rt * 16 + lkq * 4 + j;
                float v = acc[rt][nc][j] + bv;
                unsigned int p = __builtin_amdgcn_cvt_pk_fp8_f32(v, v, 0u, false);
                int col = ((nc * 16) ^ ((row & 7) << 4)) + lr;
                stile[row * 128 + col] = (unsigned char)(p & 0xFFu);
            }
        }
    }
    __syncthreads();

#pragma unroll
    for (int q = 0; q < 4; ++q) {
        int idx2 = q * 256 + t;
        int row = idx2 >> 3;
        int c16 = (idx2 & 7) * 16;
        int r = mb + row;
        if (r < M)
            *(uint4*)(out + (size_t)r * HC + n0 + c16) =
                *(const uint4*)(stile + row * 128 + (c16 ^ ((row & 7) << 4)));
    }
}

// ---------------------------------------------------------------------------
// FUSED per-node kernel — the proven r15 structure (57.0us, 32 VGPR, 65%occ):
// block = 256 thr = 1 node; head-group of 32 lanes, sub = bit4 picks which
// edge of a PAIR, q = t&15 covers 8 channels (uint2 = 8 fp8 = 8B gather),
// 1-ahead prefetch. Leaky = fmaxf(u, 0.2u). Structural attacks that LOST:
// packed v_pk_* (r11,r13), 2-deep pipe (r17), 2-block/node split (r18),
// 4-edge quads (r11,r18). Kernel is gather-service-rate-bound at ~1.5TB/s.
// ---------------------------------------------------------------------------
__global__ void fused_node(const int* __restrict__ offs,
                           const int2* __restrict__ csr,
                           const unsigned char* __restrict__ xl8,
                           const unsigned char* __restrict__ xr8,
                           const float* __restrict__ att,
                           const float* __restrict__ bias,
                           float* __restrict__ alpha_out,
                           float* __restrict__ latent, int N)
{
    __shared__ float sacc[HEADS * EMB];
    __shared__ float sinv[HEADS];

    int n   = blockIdx.x;
    int t   = threadIdx.x;
    int h   = t >> 5;         // head 0..7
    int il  = t & 31;
    int sub = il >> 4;        // edge-of-pair selector
    int q   = il & 15;        // lane within 16
    int c0  = q * 8;          // channel base (8 channels/thread)
    int uo  = h * 16 + q;     // uint2 offset within a 1024B row

    float av[8];
    {
        const float4* ap = (const float4*)(att + h * EMB + c0);
        float4 a0 = ap[0], a1 = ap[1];
        av[0]=a0.x; av[1]=a0.y; av[2]=a0.z; av[3]=a0.w;
        av[4]=a1.x; av[5]=a1.y; av[6]=a1.z; av[7]=a1.w;
    }
    const uint2* xlu = (const uint2*)xl8;
    const uint2* xru = (const uint2*)xr8;

    float rv[8];
    { uint2 r = xru[(size_t)n * 128 + uo]; cvt4(r.x, rv); cvt4(r.y, rv + 4); }

    float acc[8] = {0,0,0,0,0,0,0,0};
    float S = 0.f;
    int js = offs[n], je = offs[n + 1];

    // preload first pair (clamped)
    int jc = js + sub; if (jc >= je) jc = je - 1;
    int2  ccur   = csr[jc];
    uint2 vcur   = xlu[(size_t)ccur.y * 128 + uo];
    bool  valcur = (js + sub) < je;

    for (int j = js; j < je; j += 2) {
        // preload next pair
        int jn = j + 2 + sub;
        bool valn = jn < je;
        if (!valn) jn = je - 1;
        int2  cnxt  = csr[jn];
        uint2 vnext = xlu[(size_t)cnxt.y * 128 + uo];

        float xv[8];
        cvt4(vcur.x, xv); cvt4(vcur.y, xv + 4);
        float s0 = 0.f, s1 = 0.f;
#pragma unroll
        for (int i = 0; i < 8; i += 2) {
            float u0 = xv[i]   + rv[i];   u0 = fmaxf(u0, NEG * u0);
            float u1 = xv[i+1] + rv[i+1]; u1 = fmaxf(u1, NEG * u1);
            s0 = fmaf(av[i],   u0, s0);
            s1 = fmaf(av[i+1], u1, s1);
        }
        float sp = s0 + s1;
        sp += __shfl_xor(sp, 1);
        sp += __shfl_xor(sp, 2);
        sp += __shfl_xor(sp, 4);
        sp += __shfl_xor(sp, 8);      // full head score within 16-lane half

        float wq = valcur ? __expf(sp) : 0.f;
        if (q == 0 && valcur) alpha_out[(size_t)ccur.x * HEADS + h] = wq;
        S += wq;
#pragma unroll
        for (int i = 0; i < 8; ++i) acc[i] = fmaf(wq, xv[i], acc[i]);

        vcur = vnext; ccur = cnxt; valcur = valn;
    }

    // merge the two sub-halves
    S += __shfl_xor(S, 16);
#pragma unroll
    for (int i = 0; i < 8; ++i) acc[i] += __shfl_xor(acc[i], 16);

    float inv = 1.f / (S + 1e-16f);
    if (il == 0) sinv[h] = inv;
    if (sub == 0) {
#pragma unroll
        for (int i = 0; i < 8; ++i) sacc[h * EMB + c0 + i] = acc[i] * inv;
    }
    __syncthreads();   // stashes + sinv + sacc visible block-wide

    // Pass 2: scale stashed exp(s) by 1/S  (32 edges x 8 heads per step)
    for (int j0 = js; j0 < je; j0 += 32) {
        int j = j0 + (t >> 3);
        if (j < je) {
            int hh = t & 7;
            size_t p = (size_t)csr[j].x * HEADS + hh;
            alpha_out[p] *= sinv[hh];
        }
    }

    // Epilogue: head mean + bias
    if (t < EMB) {
        float sum = 0.f;
#pragma unroll
        for (int hh = 0; hh < HEADS; ++hh) sum += sacc[hh * EMB + t];
        latent[(size_t)n * EMB + t] = sum * 0.125f + bias[t];
    }
}

// ---------------------------------------------------------------------------
extern "C" void kernel_launch(void* const* d_in, const int* in_sizes, int n_in,
                              void* d_out, int out_size, void* d_ws, size_t ws_size,
                              hipStream_t stream)
{
    const float* x    = (const float*)d_in[0];
    const float* W_l  = (const float*)d_in[1];
    const float* b_l  = (const float*)d_in[2];
    const float* W_r  = (const float*)d_in[3];
    const float* b_r  = (const float*)d_in[4];
    const float* att  = (const float*)d_in[5];
    const float* bias = (const float*)d_in[6];
    const int*   ei   = (const int*)d_in[7];

    int N  = in_sizes[0] / EMB;     // 10000
    int E  = in_sizes[7] / 2;       // 160000
    int Et = E + N;                 // 170000

    auto align256 = [](size_t v) { return (v + 255) & ~(size_t)255; };
    char* w = (char*)d_ws;
    int* deg      = (int*)w;    w += align256((size_t)N * 4);
    int* offs     = (int*)w;    w += align256((size_t)(N + 1) * 4);
    int* cursor   = (int*)w;    w += align256((size_t)N * 4);
    int2* csr     = (int2*)w;   w += align256((size_t)Et * 8);
    unsigned char* xl8 = (unsigned char*)w;   w += align256((size_t)N * HC);
    unsigned char* xr8 = (unsigned char*)w;   w += align256((size_t)N * HC);
    __hip_bfloat16* xb  = (__hip_bfloat16*)w;  w += align256((size_t)N * EMB * 2);
    __hip_bfloat16* WtL = (__hip_bfloat16*)w;  w += align256((size_t)EMB * HC * 2);
    __hip_bfloat16* WtR = (__hip_bfloat16*)w;  w += align256((size_t)EMB * HC * 2);

    // d_out fp32: latent[N*128] | full_edge_index[2*Et] | alpha[Et*8]
    float* out_latent = (float*)d_out;
    float* out_ei     = out_latent + (size_t)N * EMB;
    float* out_alpha  = out_ei + (size_t)2 * Et;

    hipMemsetAsync(deg, 0, (size_t)N * 4, stream);

    int n4  = N * EMB / 4;
    int nbA = (n4 + 255) / 256;
    int nbB = nbA + 32;                       // 32 LDS-transpose blocks
    int nbC = nbB + (Et + 255) / 256;
    int nbD = nbC + (2 * Et + 255) / 256;
    prep<<<nbD, 256, 0, stream>>>(x, W_l, W_r, ei, xb, WtL, WtR, deg, out_ei,
                                  N, E, nbA, nbB, nbC);

    scan_offsets<<<1, 1024, 0, stream>>>(deg, N, offs, cursor);

    int nbF = (Et + 255) / 256;
    int gx = (N + 127) / 128, gy = HC / 128;
    mid<<<nbF + gx * gy * 2, 256, 0, stream>>>(ei, E, N, cursor, csr,
                                               xb, WtL, WtR, b_l, b_r,
                                               xl8, xr8, N, nbF, gx, gy);

    fused_node<<<N, 256, 0, stream>>>(offs, csr, xl8, xr8,
                                      att, bias, out_alpha, out_latent, N);
}